// Round 1
// baseline (138.342 us; speedup 1.0000x reference)
//
#include <hip/hip_runtime.h>
#include <stdint.h>

// out = tokens @ W_eff + b_eff, where W_eff folds the BULK_DIM=10 depth
// dimension with closed-form weights w_k = (1/10) * sum_{z=k..10} 1/z.
// (The reference scan is the running mean; averaging over depth gives these.)
//
// v2: the tokens fp32->bf16 cvt pass (and the Ab intermediate) is deleted.
// The GEMM reads tokens fp32 directly and converts while reg-staging into
// the same swizzled bf16 LDS layout. Saves ~49 MB of HBM round-trip.

static constexpr float FW[10] = {
    0.2928968253968254f, 0.1928968253968254f, 0.1428968253968254f,
    0.1095634920634921f, 0.0845634920634921f, 0.0645634920634921f,
    0.0478968253968254f, 0.0336111111111111f, 0.0211111111111111f,
    0.0100000000000000f};

typedef __attribute__((ext_vector_type(8))) short short8;     // 8 bf16 = 4 VGPR
typedef __attribute__((ext_vector_type(16))) float floatx16;  // 32x32 C/D frag

// round-to-nearest fp32->bf16, pack two into one uint via v_perm_b32
__device__ inline unsigned int bf16pack2(float hi, float lo) {
    unsigned int uh = __float_as_uint(hi) + 0x8000u;
    unsigned int ul = __float_as_uint(lo) + 0x8000u;
    return __builtin_amdgcn_perm(uh, ul, 0x07060302u);  // {hi[31:16], lo[31:16]}
}

#define LDS_AS(p) ((__attribute__((address_space(3))) unsigned int*)(p))
#define GLB_AS(p) ((const __attribute__((address_space(1))) unsigned int*)(p))

// ---------------------------------------------------------------------------
// Prep kernel (one launch, block-id partitioned):
//   blocks [0,512): fold_w  W_eff^T[n][k] bf16, n-major (32k x 64n tiles)
//   block  512:     fold_b  b_eff fp32
// HBM-bound: 40 MB read + 2 MB write => ~7 us.
// ---------------------------------------------------------------------------
__global__ __launch_bounds__(256) void prep(const float* __restrict__ W,
                                            const float* __restrict__ b,
                                            unsigned short* __restrict__ Wt,
                                            float* __restrict__ beff) {
    __shared__ float T[32 * 65];
    const int t = threadIdx.x;
    const int bid = blockIdx.x;

    if (bid < 512) {  // ---- fold_w
        const int n0 = (bid & 15) * 64;
        const int k0 = (bid >> 4) * 32;
#pragma unroll
        for (int s = 0; s < 2; ++s) {
            int slot = s * 256 + t;
            int r = slot >> 4;              // k-local 0..31
            int c4 = (slot & 15) * 4;       // n-local float4
            const float4* src = (const float4*)(W + (size_t)(k0 + r) * 10240 + n0 + c4);
            float4 acc = {0.f, 0.f, 0.f, 0.f};
#pragma unroll
            for (int j = 0; j < 10; ++j) {
                float4 v = src[j * 256];
                acc.x += FW[j] * v.x; acc.y += FW[j] * v.y;
                acc.z += FW[j] * v.z; acc.w += FW[j] * v.w;
            }
            T[r * 65 + c4 + 0] = acc.x;
            T[r * 65 + c4 + 1] = acc.y;
            T[r * 65 + c4 + 2] = acc.z;
            T[r * 65 + c4 + 3] = acc.w;
        }
        __syncthreads();
#pragma unroll
        for (int s = 0; s < 2; ++s) {
            int slot = s * 256 + t;
            int nl = slot >> 3;             // n-local 0..63
            int k4 = (slot & 7) * 4;        // k-local group of 4
            float f0 = T[(k4 + 0) * 65 + nl];
            float f1 = T[(k4 + 1) * 65 + nl];
            float f2 = T[(k4 + 2) * 65 + nl];
            float f3 = T[(k4 + 3) * 65 + nl];
            uint2 p;
            p.x = bf16pack2(f1, f0);
            p.y = bf16pack2(f3, f2);
            *(uint2*)(Wt + (size_t)(n0 + nl) * 1024 + k0 + k4) = p;
        }
        return;
    }
    // ---- bid == 512: fold_b
    const float4* src = (const float4*)b + t;
    float4 acc = {0.f, 0.f, 0.f, 0.f};
#pragma unroll
    for (int j = 0; j < 10; ++j) {
        float4 v = src[j * 256];
        acc.x += FW[j] * v.x; acc.y += FW[j] * v.y;
        acc.z += FW[j] * v.z; acc.w += FW[j] * v.w;
    }
    ((float4*)beff)[t] = acc;
}

// ---------------------------------------------------------------------------
// GEMM: C[8192][1024] = tokens(fp32, converted on the fly) @ Weff^T + b_eff
// 128x128 tile, 4 waves 2x2, each wave 64x64 = 2x2 of mfma_f32_32x32x16_bf16.
// BK=64, DOUBLE-BUFFERED LDS (2 x 16KB per operand = 64KB/block, 2 blocks/CU).
// B: async global_load_lds (unchanged, pre-swizzled source).
// A: reg-staged fp32 -> bf16pack2 -> ds_write_b128, same swizzled layout.
//    T14 split: loads issued right after the barrier, pack+ds_write after
//    the compute phase -> HBM latency hides under MFMA+ds_read of tile kt.
// XOR swizzle slot = row*8 + (chunk ^ (row&7)); frag ds_read_b128 2-way free.
// Grid (64,8), x = M-tile: id%8 = M-tile%8 pins A stripes per XCD
// (fp32 A stripe = 512KB, 8 stripes/XCD = 4MB = L2).
// ---------------------------------------------------------------------------
__global__ __launch_bounds__(256) void gemm32(const float* __restrict__ A,
                                              const unsigned short* __restrict__ Wt,
                                              const float* __restrict__ beff,
                                              float* __restrict__ C) {
    __shared__ __align__(16) unsigned char As[2][16384];  // 128 rows x 8 chunks x 16B
    __shared__ __align__(16) unsigned char Bs[2][16384];

    const int t = threadIdx.x;
    const int lane = t & 63;
    const int w = t >> 6;
    const int l31 = lane & 31;
    const int khalf = lane >> 5;       // 0/1: k-offset 0 or 8 within K=16
    const int wm = (w & 1) * 64;
    const int wn = (w >> 1) * 64;
    const int bm = blockIdx.x * 128;   // x fastest -> id%8 = M-tile%8 (XCD pin)
    const int bn = blockIdx.y * 128;

    floatx16 acc[2][2];
#pragma unroll
    for (int i = 0; i < 2; ++i)
#pragma unroll
        for (int j = 0; j < 2; ++j)
#pragma unroll
            for (int r = 0; r < 16; ++r) acc[i][j][r] = 0.f;

    const char* Abase = (const char*)A + (size_t)bm * 4096;   // fp32 rows
    const char* Bbase = (const char*)Wt + (size_t)bn * 2048;  // bf16 rows

    // staging geometry: 1024 slots of 16B (bf16) per operand, 4 slots/thread.
    // LDS slot s holds logical (row m = s>>3, chunk c = (s&7)^(m&7)); the
    // XOR makes the compute-side ds_read_b128 2-way-free.
    const int sI = w * 4;
    int sm[4], sc[4];
#pragma unroll
    for (int i = 0; i < 4; ++i) {
        int s = (sI + i) * 64 + lane;
        sm[i] = s >> 3;
        sc[i] = (s & 7) ^ (sm[i] & 7);
    }

    float4 ar[4][2];  // in-flight A fp32 (8 floats per slot)

    // ---- prologue: stage tile 0
#pragma unroll
    for (int i = 0; i < 4; ++i) {
        const float4* ga = (const float4*)(Abase + (size_t)sm[i] * 4096 + sc[i] * 32);
        ar[i][0] = ga[0];
        ar[i][1] = ga[1];
    }
#pragma unroll
    for (int i = 0; i < 4; ++i) {
        __builtin_amdgcn_global_load_lds(GLB_AS(Bbase + (size_t)sm[i] * 2048 + sc[i] * 16),
                                         LDS_AS(Bs[0] + (sI + i) * 1024), 16, 0, 0);
    }
#pragma unroll
    for (int i = 0; i < 4; ++i) {
        uint4 p;
        p.x = bf16pack2(ar[i][0].y, ar[i][0].x);
        p.y = bf16pack2(ar[i][0].w, ar[i][0].z);
        p.z = bf16pack2(ar[i][1].y, ar[i][1].x);
        p.w = bf16pack2(ar[i][1].w, ar[i][1].z);
        *(uint4*)(As[0] + (sI + i) * 1024 + lane * 16) = p;
    }

#pragma unroll
    for (int kt = 0; kt < 16; ++kt) {
        __syncthreads();  // tile kt staged (A ds_writes + B async loads drained)

        const int buf = (kt + 1) & 1;
        if (kt < 15) {    // issue prefetch of tile kt+1 (loads only; writes later)
            const int k0n = (kt + 1) * 64;
#pragma unroll
            for (int i = 0; i < 4; ++i) {
                const float4* ga = (const float4*)(Abase + (size_t)sm[i] * 4096 +
                                                   (size_t)k0n * 4 + sc[i] * 32);
                ar[i][0] = ga[0];
                ar[i][1] = ga[1];
            }
#pragma unroll
            for (int i = 0; i < 4; ++i) {
                __builtin_amdgcn_global_load_lds(
                    GLB_AS(Bbase + (size_t)sm[i] * 2048 + (size_t)k0n * 2 + sc[i] * 16),
                    LDS_AS(Bs[buf] + (sI + i) * 1024), 16, 0, 0);
            }
        }

        const unsigned char* Acur = As[kt & 1];
        const unsigned char* Bcur = Bs[kt & 1];
#pragma unroll
        for (int kk = 0; kk < 4; ++kk) {
            int c = kk * 2 + khalf;        // logical chunk 0..7
            short8 af[2], bf[2];
#pragma unroll
            for (int tm = 0; tm < 2; ++tm) {
                int m = wm + tm * 32 + l31;
                int slot = m * 8 + (c ^ (m & 7));
                af[tm] = *(const short8*)(Acur + slot * 16);
            }
#pragma unroll
            for (int tn = 0; tn < 2; ++tn) {
                int n = wn + tn * 32 + l31;
                int slot = n * 8 + (c ^ (n & 7));
                bf[tn] = *(const short8*)(Bcur + slot * 16);
            }
#pragma unroll
            for (int tm = 0; tm < 2; ++tm)
#pragma unroll
                for (int tn = 0; tn < 2; ++tn)
                    acc[tm][tn] = __builtin_amdgcn_mfma_f32_32x32x16_bf16(
                        af[tm], bf[tn], acc[tm][tn], 0, 0, 0);
        }

        if (kt < 15) {    // convert + publish A tile kt+1 into the other buffer
#pragma unroll
            for (int i = 0; i < 4; ++i) {
                uint4 p;
                p.x = bf16pack2(ar[i][0].y, ar[i][0].x);
                p.y = bf16pack2(ar[i][0].w, ar[i][0].z);
                p.z = bf16pack2(ar[i][1].y, ar[i][1].x);
                p.w = bf16pack2(ar[i][1].w, ar[i][1].z);
                *(uint4*)(As[buf] + (sI + i) * 1024 + lane * 16) = p;
            }
        }
    }

    // epilogue: col = lane&31, row = (reg&3) + 8*(reg>>2) + 4*(lane>>5)
#pragma unroll
    for (int tn = 0; tn < 2; ++tn) {
        int col = bn + wn + tn * 32 + l31;
        float bias = beff[col];
#pragma unroll
        for (int tm = 0; tm < 2; ++tm) {
            int rbase = bm + wm + tm * 32 + 4 * khalf;
#pragma unroll
            for (int r = 0; r < 16; ++r) {
                int row = rbase + (r & 3) + 8 * (r >> 2);
                C[(size_t)row * 1024 + col] = acc[tm][tn][r] + bias;
            }
        }
    }
}

extern "C" void kernel_launch(void* const* d_in, const int* in_sizes, int n_in,
                              void* d_out, int out_size, void* d_ws, size_t ws_size,
                              hipStream_t stream) {
    const float* tokens = (const float*)d_in[0];  // (4,2048,1024) fp32
    const float* W      = (const float*)d_in[1];  // (1024, 10240) fp32
    const float* b      = (const float*)d_in[2];  // (10240,) fp32
    float* out = (float*)d_out;                   // (4,2048,1024) fp32

    unsigned short* Wt = (unsigned short*)d_ws;            // 2 MB bf16
    float* beff = (float*)((char*)d_ws + 2097152);         // 4 KB fp32
    // required ws: 2101248 B (same minimum as the previous version)

    prep<<<513, 256, 0, stream>>>(W, b, Wt, beff);
    gemm32<<<dim3(64, 8), 256, 0, stream>>>(tokens, Wt, beff, out);
}

// Round 2
// 131.716 us; speedup vs baseline: 1.0503x; 1.0503x over previous
//
#include <hip/hip_runtime.h>
#include <stdint.h>

// out = tokens @ W_eff + b_eff, where W_eff folds the BULK_DIM=10 depth
// dimension with closed-form weights w_k = (1/10) * sum_{z=k..10} 1/z.
// (The reference scan is the running mean; averaging over depth gives these.)
//
// v3: same fused structure as v2 (GEMM reads tokens fp32, converts in-reg,
// ds_writes swizzled bf16 into LDS) but with sched_barrier(0) fences pinning
// the {stage-issue | compute | pack+ds_write} phases. v2's counters showed
// VGPR=88 (< the 64 acc + 32 in-flight A minimum): the compiler had SUNK the
// A global loads to the pack site, serializing load->wait->pack per tile
// (gemm 57.9us, everything <13% busy). The fences force the loads to stay
// issued a full compute phase before their use.

static constexpr float FW[10] = {
    0.2928968253968254f, 0.1928968253968254f, 0.1428968253968254f,
    0.1095634920634921f, 0.0845634920634921f, 0.0645634920634921f,
    0.0478968253968254f, 0.0336111111111111f, 0.0211111111111111f,
    0.0100000000000000f};

typedef __attribute__((ext_vector_type(8))) short short8;     // 8 bf16 = 4 VGPR
typedef __attribute__((ext_vector_type(16))) float floatx16;  // 32x32 C/D frag

// round-to-nearest fp32->bf16, pack two into one uint via v_perm_b32
__device__ inline unsigned int bf16pack2(float hi, float lo) {
    unsigned int uh = __float_as_uint(hi) + 0x8000u;
    unsigned int ul = __float_as_uint(lo) + 0x8000u;
    return __builtin_amdgcn_perm(uh, ul, 0x07060302u);  // {hi[31:16], lo[31:16]}
}

#define LDS_AS(p) ((__attribute__((address_space(3))) unsigned int*)(p))
#define GLB_AS(p) ((const __attribute__((address_space(1))) unsigned int*)(p))

// ---------------------------------------------------------------------------
// Prep kernel (one launch, block-id partitioned):
//   blocks [0,512): fold_w  W_eff^T[n][k] bf16, n-major (32k x 64n tiles)
//   block  512:     fold_b  b_eff fp32
// HBM-bound: 40 MB read + 2 MB write => ~7 us.
// ---------------------------------------------------------------------------
__global__ __launch_bounds__(256) void prep(const float* __restrict__ W,
                                            const float* __restrict__ b,
                                            unsigned short* __restrict__ Wt,
                                            float* __restrict__ beff) {
    __shared__ float T[32 * 65];
    const int t = threadIdx.x;
    const int bid = blockIdx.x;

    if (bid < 512) {  // ---- fold_w
        const int n0 = (bid & 15) * 64;
        const int k0 = (bid >> 4) * 32;
#pragma unroll
        for (int s = 0; s < 2; ++s) {
            int slot = s * 256 + t;
            int r = slot >> 4;              // k-local 0..31
            int c4 = (slot & 15) * 4;       // n-local float4
            const float4* src = (const float4*)(W + (size_t)(k0 + r) * 10240 + n0 + c4);
            float4 acc = {0.f, 0.f, 0.f, 0.f};
#pragma unroll
            for (int j = 0; j < 10; ++j) {
                float4 v = src[j * 256];
                acc.x += FW[j] * v.x; acc.y += FW[j] * v.y;
                acc.z += FW[j] * v.z; acc.w += FW[j] * v.w;
            }
            T[r * 65 + c4 + 0] = acc.x;
            T[r * 65 + c4 + 1] = acc.y;
            T[r * 65 + c4 + 2] = acc.z;
            T[r * 65 + c4 + 3] = acc.w;
        }
        __syncthreads();
#pragma unroll
        for (int s = 0; s < 2; ++s) {
            int slot = s * 256 + t;
            int nl = slot >> 3;             // n-local 0..63
            int k4 = (slot & 7) * 4;        // k-local group of 4
            float f0 = T[(k4 + 0) * 65 + nl];
            float f1 = T[(k4 + 1) * 65 + nl];
            float f2 = T[(k4 + 2) * 65 + nl];
            float f3 = T[(k4 + 3) * 65 + nl];
            uint2 p;
            p.x = bf16pack2(f1, f0);
            p.y = bf16pack2(f3, f2);
            *(uint2*)(Wt + (size_t)(n0 + nl) * 1024 + k0 + k4) = p;
        }
        return;
    }
    // ---- bid == 512: fold_b
    const float4* src = (const float4*)b + t;
    float4 acc = {0.f, 0.f, 0.f, 0.f};
#pragma unroll
    for (int j = 0; j < 10; ++j) {
        float4 v = src[j * 256];
        acc.x += FW[j] * v.x; acc.y += FW[j] * v.y;
        acc.z += FW[j] * v.z; acc.w += FW[j] * v.w;
    }
    ((float4*)beff)[t] = acc;
}

// ---------------------------------------------------------------------------
// GEMM: C[8192][1024] = tokens(fp32, converted on the fly) @ Weff^T + b_eff
// 128x128 tile, 4 waves 2x2, each wave 64x64 = 2x2 of mfma_f32_32x32x16_bf16.
// BK=64, DOUBLE-BUFFERED LDS (2 x 16KB per operand = 64KB/block, 2 blocks/CU).
// B: async global_load_lds (pre-swizzled source).
// A: reg-staged fp32 -> bf16pack2 -> ds_write_b128, same swizzled layout.
// Phase pinning per iter (sched_barrier(0) fences, compiler waits intact):
//   [A loads kt+1 (8x dwordx4), B gll kt+1 (4x)] | [ds_read+MFMA kt] |
//   [vmcnt(4) -> pack+ds_write kt+1] -> __syncthreads (vmcnt0/lgkm0 drain).
// A loads issued BEFORE B glls so the pre-pack wait is vmcnt(4), not 0.
// XOR swizzle slot = row*8 + (chunk ^ (row&7)); frag ds_read_b128 2-way free.
// Grid (64,8), x = M-tile: id%8 = M-tile%8 pins A stripes per XCD.
// ---------------------------------------------------------------------------
__global__ __launch_bounds__(256) void gemm32(const float* __restrict__ A,
                                              const unsigned short* __restrict__ Wt,
                                              const float* __restrict__ beff,
                                              float* __restrict__ C) {
    __shared__ __align__(16) unsigned char As[2][16384];  // 128 rows x 8 chunks x 16B
    __shared__ __align__(16) unsigned char Bs[2][16384];

    const int t = threadIdx.x;
    const int lane = t & 63;
    const int w = t >> 6;
    const int l31 = lane & 31;
    const int khalf = lane >> 5;       // 0/1: k-offset 0 or 8 within K=16
    const int wm = (w & 1) * 64;
    const int wn = (w >> 1) * 64;
    const int bm = blockIdx.x * 128;   // x fastest -> id%8 = M-tile%8 (XCD pin)
    const int bn = blockIdx.y * 128;

    floatx16 acc[2][2];
#pragma unroll
    for (int i = 0; i < 2; ++i)
#pragma unroll
        for (int j = 0; j < 2; ++j)
#pragma unroll
            for (int r = 0; r < 16; ++r) acc[i][j][r] = 0.f;

    const char* Abase = (const char*)A + (size_t)bm * 4096;   // fp32 rows
    const char* Bbase = (const char*)Wt + (size_t)bn * 2048;  // bf16 rows

    // staging geometry: 1024 slots of 16B (bf16) per operand, 4 slots/thread.
    // LDS slot s holds logical (row m = s>>3, chunk c = (s&7)^(m&7)); the
    // XOR makes the compute-side ds_read_b128 2-way-free.
    const int sI = w * 4;
    int sm[4], sc[4];
#pragma unroll
    for (int i = 0; i < 4; ++i) {
        int s = (sI + i) * 64 + lane;
        sm[i] = s >> 3;
        sc[i] = (s & 7) ^ (sm[i] & 7);
    }

    float4 ar[4][2];  // in-flight A fp32 (8 floats per slot) — must stay live

    // ---- prologue: stage tile 0
#pragma unroll
    for (int i = 0; i < 4; ++i) {
        const float4* ga = (const float4*)(Abase + (size_t)sm[i] * 4096 + sc[i] * 32);
        ar[i][0] = ga[0];
        ar[i][1] = ga[1];
    }
#pragma unroll
    for (int i = 0; i < 4; ++i) {
        __builtin_amdgcn_global_load_lds(GLB_AS(Bbase + (size_t)sm[i] * 2048 + sc[i] * 16),
                                         LDS_AS(Bs[0] + (sI + i) * 1024), 16, 0, 0);
    }
#pragma unroll
    for (int i = 0; i < 4; ++i) {
        uint4 p;
        p.x = bf16pack2(ar[i][0].y, ar[i][0].x);
        p.y = bf16pack2(ar[i][0].w, ar[i][0].z);
        p.z = bf16pack2(ar[i][1].y, ar[i][1].x);
        p.w = bf16pack2(ar[i][1].w, ar[i][1].z);
        *(uint4*)(As[0] + (sI + i) * 1024 + lane * 16) = p;
    }

#pragma unroll
    for (int kt = 0; kt < 16; ++kt) {
        __syncthreads();  // tile kt staged

        const int buf = (kt + 1) & 1;
        if (kt < 15) {    // ---- phase 1: issue loads for tile kt+1 (A first!)
            const int k0n = (kt + 1) * 64;
#pragma unroll
            for (int i = 0; i < 4; ++i) {
                const float4* ga = (const float4*)(Abase + (size_t)sm[i] * 4096 +
                                                   (size_t)k0n * 4 + sc[i] * 32);
                ar[i][0] = ga[0];
                ar[i][1] = ga[1];
            }
#pragma unroll
            for (int i = 0; i < 4; ++i) {
                __builtin_amdgcn_global_load_lds(
                    GLB_AS(Bbase + (size_t)sm[i] * 2048 + (size_t)k0n * 2 + sc[i] * 16),
                    LDS_AS(Bs[buf] + (sI + i) * 1024), 16, 0, 0);
            }
        }
        // fence: loads stay above (cannot sink into / below compute)
        __builtin_amdgcn_sched_barrier(0);

        // ---- phase 2: compute tile kt
        const unsigned char* Acur = As[kt & 1];
        const unsigned char* Bcur = Bs[kt & 1];
#pragma unroll
        for (int kk = 0; kk < 4; ++kk) {
            int c = kk * 2 + khalf;        // logical chunk 0..7
            short8 af[2], bf[2];
#pragma unroll
            for (int tm = 0; tm < 2; ++tm) {
                int m = wm + tm * 32 + l31;
                int slot = m * 8 + (c ^ (m & 7));
                af[tm] = *(const short8*)(Acur + slot * 16);
            }
#pragma unroll
            for (int tn = 0; tn < 2; ++tn) {
                int n = wn + tn * 32 + l31;
                int slot = n * 8 + (c ^ (n & 7));
                bf[tn] = *(const short8*)(Bcur + slot * 16);
            }
#pragma unroll
            for (int tm = 0; tm < 2; ++tm)
#pragma unroll
                for (int tn = 0; tn < 2; ++tn)
                    acc[tm][tn] = __builtin_amdgcn_mfma_f32_32x32x16_bf16(
                        af[tm], bf[tn], acc[tm][tn], 0, 0, 0);
        }
        // fence: pack cannot hoist above compute (keeps the vmcnt wait late)
        __builtin_amdgcn_sched_barrier(0);

        if (kt < 15) {    // ---- phase 3: convert + publish A tile kt+1
#pragma unroll
            for (int i = 0; i < 4; ++i) {
                uint4 p;
                p.x = bf16pack2(ar[i][0].y, ar[i][0].x);
                p.y = bf16pack2(ar[i][0].w, ar[i][0].z);
                p.z = bf16pack2(ar[i][1].y, ar[i][1].x);
                p.w = bf16pack2(ar[i][1].w, ar[i][1].z);
                *(uint4*)(As[buf] + (sI + i) * 1024 + lane * 16) = p;
            }
        }
    }

    // epilogue: col = lane&31, row = (reg&3) + 8*(reg>>2) + 4*(lane>>5)
#pragma unroll
    for (int tn = 0; tn < 2; ++tn) {
        int col = bn + wn + tn * 32 + l31;
        float bias = beff[col];
#pragma unroll
        for (int tm = 0; tm < 2; ++tm) {
            int rbase = bm + wm + tm * 32 + 4 * khalf;
#pragma unroll
            for (int r = 0; r < 16; ++r) {
                int row = rbase + (r & 3) + 8 * (r >> 2);
                C[(size_t)row * 1024 + col] = acc[tm][tn][r] + bias;
            }
        }
    }
}

extern "C" void kernel_launch(void* const* d_in, const int* in_sizes, int n_in,
                              void* d_out, int out_size, void* d_ws, size_t ws_size,
                              hipStream_t stream) {
    const float* tokens = (const float*)d_in[0];  // (4,2048,1024) fp32
    const float* W      = (const float*)d_in[1];  // (1024, 10240) fp32
    const float* b      = (const float*)d_in[2];  // (10240,) fp32
    float* out = (float*)d_out;                   // (4,2048,1024) fp32

    unsigned short* Wt = (unsigned short*)d_ws;            // 2 MB bf16
    float* beff = (float*)((char*)d_ws + 2097152);         // 4 KB fp32
    // required ws: 2101248 B

    prep<<<513, 256, 0, stream>>>(W, b, Wt, beff);
    gemm32<<<dim3(64, 8), 256, 0, stream>>>(tokens, Wt, beff, out);
}